// Round 3
// baseline (608.754 us; speedup 1.0000x reference)
//
#include <hip/hip_runtime.h>

#define NN   50000
#define FIN  256
#define C1   64        // HEADS*HID
#define NH   8
#define NHID 8
#define NC   16
#define NE   1600000
#define NTOT (NE + NN)
#define NBLK_SCAN ((NN + 255) / 256)   // 196
#define NB   782       // buckets of 64 dst nodes: (50000+63)/64
#define BCAP 3968      // per-bucket capacity (mean 2112, +40 sigma)

// ---- workspace layout (float-indexed), 35.8 MB total ----
#define OFF_H1   0              // h1 [NN*C1]; later reused: h2 @0, als2 @800000, ald2 @850000
#define OFF_H2   0
#define OFF_ALS2 800000
#define OFF_ALD2 850000
#define OFF_G1   3200000        // g1 [NN*C1]; ALSO bucket area during sort (NB*BCAP=3,102,976 ints)
#define OFF_ALS1 6400000
#define OFF_ALD1 6800000
#define OFF_CNT  7200000        // int[50000]
#define OFF_BSUM 7250048        // int[256]
#define OFF_OFFS 7250304        // int[50001]
#define OFF_BCUR 7300352        // int[NB]
#define OFF_SRC  7301248        // int[NTOT]
// end = 8,951,248 floats = 35.8 MB

// ---------------- K1: h1 = x @ W1  (50000x256 @ 256x64) ----------------
__global__ __launch_bounds__(256) void k_gemm1(const float* __restrict__ x,
                                               const float* __restrict__ W1,
                                               float* __restrict__ h1) {
    __shared__ float xs[64][68];
    __shared__ float ws[64][64];
    const int tid = threadIdx.x;
    const int tx = tid & 15, ty = tid >> 4;
    const int r0 = blockIdx.x * 64;
    float acc[4][4] = {};
    for (int k0 = 0; k0 < FIN; k0 += 64) {
        #pragma unroll
        for (int it = 0; it < 4; ++it) {
            int rloc = it * 16 + ty;
            int grow = r0 + rloc;
            float4 v = make_float4(0.f, 0.f, 0.f, 0.f);
            if (grow < NN) v = *(const float4*)(&x[(size_t)grow * FIN + k0 + tx * 4]);
            *(float4*)(&xs[rloc][tx * 4]) = v;
        }
        #pragma unroll
        for (int it = 0; it < 4; ++it) {
            int kk = it * 16 + ty;
            float4 v = *(const float4*)(&W1[(size_t)(k0 + kk) * C1 + tx * 4]);
            *(float4*)(&ws[kk][tx * 4]) = v;
        }
        __syncthreads();
        #pragma unroll 8
        for (int kk = 0; kk < 64; ++kk) {
            float4 wv = *(const float4*)(&ws[kk][tx * 4]);
            #pragma unroll
            for (int m = 0; m < 4; ++m) {
                float xv = xs[m * 16 + ty][kk];
                acc[m][0] += xv * wv.x;
                acc[m][1] += xv * wv.y;
                acc[m][2] += xv * wv.z;
                acc[m][3] += xv * wv.w;
            }
        }
        __syncthreads();
    }
    #pragma unroll
    for (int m = 0; m < 4; ++m) {
        int grow = r0 + m * 16 + ty;
        if (grow < NN) {
            float4 v = make_float4(acc[m][0], acc[m][1], acc[m][2], acc[m][3]);
            *(float4*)(&h1[(size_t)grow * C1 + tx * 4]) = v;
        }
    }
}

// ---------------- K1b: attention logits per (node, head) ----------------
__global__ __launch_bounds__(256) void k_logits1(const float* __restrict__ h1,
                                                 const float* __restrict__ a_src,
                                                 const float* __restrict__ a_dst,
                                                 float* __restrict__ als,
                                                 float* __restrict__ ald) {
    int i = blockIdx.x * 256 + threadIdx.x;   // i = n*8 + head
    if (i >= NN * NH) return;
    int n = i >> 3, hd = i & 7;
    const float4* hp = (const float4*)(&h1[(size_t)n * C1 + hd * NHID]);
    float4 h0 = hp[0], h1v = hp[1];
    const float4* asp = (const float4*)(&a_src[hd * NHID]);
    float4 a0 = asp[0], a1 = asp[1];
    const float4* adp = (const float4*)(&a_dst[hd * NHID]);
    float4 d0 = adp[0], d1 = adp[1];
    float s = h0.x * a0.x + h0.y * a0.y + h0.z * a0.z + h0.w * a0.w
            + h1v.x * a1.x + h1v.y * a1.y + h1v.z * a1.z + h1v.w * a1.w;
    float d = h0.x * d0.x + h0.y * d0.y + h0.z * d0.z + h0.w * d0.w
            + h1v.x * d1.x + h1v.y * d1.y + h1v.z * d1.z + h1v.w * d1.w;
    als[i] = s;
    ald[i] = d;
}

// ---------------- sort phase A: bucket by dst>>6, packed (src<<6)|dlocal --
__global__ __launch_bounds__(256) void k_bucket(const int* __restrict__ ei,
                                                int* __restrict__ bcur,
                                                int* __restrict__ bucket) {
    for (int e = blockIdx.x * 256 + threadIdx.x; e < NTOT; e += gridDim.x * 256) {
        int s, d;
        if (e < NE) { s = ei[e]; d = ei[NE + e]; }
        else        { s = e - NE; d = s; }
        int b = d >> 6;
        int pos = atomicAdd(&bcur[b], 1);
        if (pos < BCAP) bucket[b * BCAP + pos] = (s << 6) | (d & 63);
    }
}

// ---------------- sort phase B1: per-bucket LDS histogram -> cnt[d] -------
__global__ __launch_bounds__(256) void k_bhist(const int* __restrict__ bcur,
                                               const int* __restrict__ bucket,
                                               int* __restrict__ cnt) {
    __shared__ int lc[64];
    int b = blockIdx.x;
    if (threadIdx.x < 64) lc[threadIdx.x] = 0;
    __syncthreads();
    int n = bcur[b]; if (n > BCAP) n = BCAP;
    const int* bp = &bucket[b * BCAP];
    for (int i = threadIdx.x; i < n; i += 256)
        atomicAdd(&lc[bp[i] & 63], 1);
    __syncthreads();
    if (threadIdx.x < 64) {
        int d = b * 64 + threadIdx.x;
        if (d < NN) cnt[d] = lc[threadIdx.x];
    }
}

// ---------------- scan: cnt -> offs (exclusive) ----------------
__global__ __launch_bounds__(256) void k_scan1(const int* __restrict__ cnt,
                                               int* __restrict__ bsum) {
    __shared__ int red[256];
    int i = blockIdx.x * 256 + threadIdx.x;
    red[threadIdx.x] = (i < NN) ? cnt[i] : 0;
    __syncthreads();
    for (int s = 128; s > 0; s >>= 1) {
        if (threadIdx.x < s) red[threadIdx.x] += red[threadIdx.x + s];
        __syncthreads();
    }
    if (threadIdx.x == 0) bsum[blockIdx.x] = red[0];
}

__global__ __launch_bounds__(64) void k_scan2(int* __restrict__ bsum,
                                              int* __restrict__ offs) {
    if (threadIdx.x == 0) {
        int run = 0;
        for (int b = 0; b < NBLK_SCAN; ++b) {
            int t = bsum[b];
            bsum[b] = run;
            run += t;
        }
        offs[NN] = NTOT;
    }
}

__global__ __launch_bounds__(256) void k_scan3(const int* __restrict__ cnt,
                                               const int* __restrict__ bsum,
                                               int* __restrict__ offs) {
    __shared__ int sc[256];
    int i = blockIdx.x * 256 + threadIdx.x;
    int v = (i < NN) ? cnt[i] : 0;
    sc[threadIdx.x] = v;
    __syncthreads();
    for (int s = 1; s < 256; s <<= 1) {
        int t = (threadIdx.x >= s) ? sc[threadIdx.x - s] : 0;
        __syncthreads();
        sc[threadIdx.x] += t;
        __syncthreads();
    }
    if (i < NN) offs[i] = bsum[blockIdx.x] + sc[threadIdx.x] - v;
}

// ---------------- sort phase B2: per-bucket scatter into CSR --------------
__global__ __launch_bounds__(256) void k_bsort(const int* __restrict__ bcur,
                                               const int* __restrict__ bucket,
                                               const int* __restrict__ offs,
                                               int* __restrict__ sorted_src) {
    __shared__ int lcur[64];
    int b = blockIdx.x;
    if (threadIdx.x < 64) {
        int d = b * 64 + threadIdx.x;
        lcur[threadIdx.x] = (d < NN) ? offs[d] : 0;
    }
    __syncthreads();
    int n = bcur[b]; if (n > BCAP) n = BCAP;
    const int* bp = &bucket[b * BCAP];
    for (int i = threadIdx.x; i < n; i += 256) {
        int v = bp[i];
        int pos = atomicAdd(&lcur[v & 63], 1);
        sorted_src[pos] = v >> 6;
    }
}

// ---------------- K2: layer-1 aggregation, gather side (no atomics) -------
__global__ __launch_bounds__(256) void k_agg1(const int* __restrict__ offs,
                                              const int* __restrict__ src,
                                              const float* __restrict__ h1,
                                              const float* __restrict__ als,
                                              const float* __restrict__ ald,
                                              const float* __restrict__ b1,
                                              float* __restrict__ g1) {
    int d = blockIdx.x * 4 + (threadIdx.x >> 6);
    if (d >= NN) return;
    int c = threadIdx.x & 63;
    int h = c >> 3;
    int beg = offs[d], end = offs[d + 1];
    float aldv = ald[d * NH + h];
    float acc = 0.f, den = 0.f;
    int i = beg;
    for (; i + 1 < end; i += 2) {
        int s0 = src[i], s1 = src[i + 1];
        float l0 = als[s0 * NH + h] + aldv;
        float l1 = als[s1 * NH + h] + aldv;
        l0 = l0 > 0.f ? l0 : 0.2f * l0;
        l1 = l1 > 0.f ? l1 : 0.2f * l1;
        float e0 = __expf(l0), e1 = __expf(l1);
        acc += e0 * h1[(size_t)s0 * C1 + c] + e1 * h1[(size_t)s1 * C1 + c];
        den += e0 + e1;
    }
    if (i < end) {
        int s0 = src[i];
        float l0 = als[s0 * NH + h] + aldv;
        l0 = l0 > 0.f ? l0 : 0.2f * l0;
        float e0 = __expf(l0);
        acc += e0 * h1[(size_t)s0 * C1 + c];
        den += e0;
    }
    float o = acc / den + b1[c];
    g1[(size_t)d * C1 + c] = o > 0.f ? o : (__expf(o) - 1.f);
}

// ---------------- K3: GEMM2 (64->16) + layer-2 logits ----------------
__global__ __launch_bounds__(256) void k_gemm2(const float* __restrict__ g1,
                                               const float* __restrict__ W2,
                                               const float* __restrict__ as2,
                                               const float* __restrict__ ad2,
                                               float* __restrict__ h2,
                                               float* __restrict__ als2,
                                               float* __restrict__ ald2) {
    __shared__ float w2s[C1][NC];
    __shared__ float hact[16][C1 + 4];
    int tid = threadIdx.x;
    for (int i = tid; i < C1 * NC; i += 256) w2s[i >> 4][i & 15] = W2[i];
    int ln = tid >> 4, j = tid & 15;
    int n = blockIdx.x * 16 + ln;
    if (n < NN) {
        float4 v = *(const float4*)(&g1[(size_t)n * C1 + j * 4]);
        *(float4*)(&hact[ln][j * 4]) = v;
    }
    __syncthreads();
    if (n < NN) {
        float sum = 0.f;
        #pragma unroll
        for (int c = 0; c < C1; ++c) sum += hact[ln][c] * w2s[c][j];
        h2[(size_t)n * NC + j] = sum;
        float ps = sum * as2[j], pd = sum * ad2[j];
        #pragma unroll
        for (int w = 1; w < 16; w <<= 1) {
            ps += __shfl_xor(ps, w);
            pd += __shfl_xor(pd, w);
        }
        if (j == 0) { als2[n] = ps; ald2[n] = pd; }
    }
}

// ---------------- K4: layer-2 aggregation + log_softmax ----------------
__global__ __launch_bounds__(256) void k_agg2(const int* __restrict__ offs,
                                              const int* __restrict__ src,
                                              const float* __restrict__ h2,
                                              const float* __restrict__ als2,
                                              const float* __restrict__ ald2,
                                              const float* __restrict__ b2,
                                              float* __restrict__ out) {
    int d = blockIdx.x * 16 + (threadIdx.x >> 4);
    if (d >= NN) return;
    int c = threadIdx.x & 15;
    int beg = offs[d], end = offs[d + 1];
    float aldv = ald2[d];
    float acc = 0.f, den = 0.f;
    int i = beg;
    for (; i + 1 < end; i += 2) {
        int s0 = src[i], s1 = src[i + 1];
        float l0 = als2[s0] + aldv;
        float l1 = als2[s1] + aldv;
        l0 = l0 > 0.f ? l0 : 0.2f * l0;
        l1 = l1 > 0.f ? l1 : 0.2f * l1;
        float e0 = __expf(l0), e1 = __expf(l1);
        acc += e0 * h2[(size_t)s0 * NC + c] + e1 * h2[(size_t)s1 * NC + c];
        den += e0 + e1;
    }
    if (i < end) {
        int s0 = src[i];
        float l0 = als2[s0] + aldv;
        l0 = l0 > 0.f ? l0 : 0.2f * l0;
        float e0 = __expf(l0);
        acc += e0 * h2[(size_t)s0 * NC + c];
        den += e0;
    }
    float o = acc / den + b2[c];
    float m = o;
    #pragma unroll
    for (int w = 1; w < 16; w <<= 1) m = fmaxf(m, __shfl_xor(m, w));
    float ex = __expf(o - m);
    float sm = ex;
    #pragma unroll
    for (int w = 1; w < 16; w <<= 1) sm += __shfl_xor(sm, w);
    out[(size_t)d * NC + c] = o - m - __logf(sm);
}

extern "C" void kernel_launch(void* const* d_in, const int* in_sizes, int n_in,
                              void* d_out, int out_size, void* d_ws, size_t ws_size,
                              hipStream_t stream) {
    const float* x   = (const float*)d_in[0];
    const int*   ei  = (const int*)  d_in[1];
    const float* W1  = (const float*)d_in[2];
    const float* as1 = (const float*)d_in[3];
    const float* ad1 = (const float*)d_in[4];
    const float* b1  = (const float*)d_in[5];
    const float* W2  = (const float*)d_in[6];
    const float* as2 = (const float*)d_in[7];
    const float* ad2 = (const float*)d_in[8];
    const float* b2  = (const float*)d_in[9];
    float* ws  = (float*)d_ws;
    float* out = (float*)d_out;

    float* h1   = ws + OFF_H1;
    float* g1   = ws + OFF_G1;
    float* als1 = ws + OFF_ALS1;
    float* ald1 = ws + OFF_ALD1;
    float* h2   = ws + OFF_H2;
    float* als2 = ws + OFF_ALS2;
    float* ald2 = ws + OFF_ALD2;
    int* cnt    = (int*)(ws + OFF_CNT);
    int* bsum   = (int*)(ws + OFF_BSUM);
    int* offs   = (int*)(ws + OFF_OFFS);
    int* bcur   = (int*)(ws + OFF_BCUR);
    int* ssrc   = (int*)(ws + OFF_SRC);
    int* bucket = (int*)(ws + OFF_G1);   // aliases g1 (dead before k_agg1 writes g1)

    // zero the bucket cursors (3 KB)
    hipMemsetAsync(bcur, 0, (size_t)NB * sizeof(int), stream);

    k_gemm1  <<<(NN + 63) / 64,         256, 0, stream>>>(x, W1, h1);
    k_logits1<<<(NN * NH + 255) / 256,  256, 0, stream>>>(h1, as1, ad1, als1, ald1);
    k_bucket <<<2048,                   256, 0, stream>>>(ei, bcur, bucket);
    k_bhist  <<<NB,                     256, 0, stream>>>(bcur, bucket, cnt);
    k_scan1  <<<NBLK_SCAN,              256, 0, stream>>>(cnt, bsum);
    k_scan2  <<<1,                       64, 0, stream>>>(bsum, offs);
    k_scan3  <<<NBLK_SCAN,              256, 0, stream>>>(cnt, bsum, offs);
    k_bsort  <<<NB,                     256, 0, stream>>>(bcur, bucket, offs, ssrc);
    k_agg1   <<<(NN + 3) / 4,           256, 0, stream>>>(offs, ssrc, h1, als1, ald1, b1, g1);
    k_gemm2  <<<(NN + 15) / 16,         256, 0, stream>>>(g1, W2, as2, ad2, h2, als2, ald2);
    k_agg2   <<<(NN + 15) / 16,         256, 0, stream>>>(offs, ssrc, h2, als2, ald2, b2, out);
}

// Round 4
// 231.242 us; speedup vs baseline: 2.6325x; 2.6325x over previous
//
#include <hip/hip_runtime.h>

#define NN   50000
#define FIN  256
#define C1   64        // HEADS*HID
#define NH   8
#define NHID 8
#define NC   16
#define NE   1600000
#define NTOT (NE + NN)

#define CH   256                        // pass-1 chunks
#define EPC  ((NTOT + CH - 1) / CH)     // 6446 edges per chunk
#define NCB  196                        // coarse buckets: dst>>8, (50000+255)/256

// ---- workspace layout (float-indexed), ~36.0 MB total ----
#define OFF_H1    0          // h1 [NN*C1]; later reused: h2 @0, als2 @800000, ald2 @850000
#define OFF_H2    0
#define OFF_ALS2  800000
#define OFF_ALD2  850000
#define OFF_G1    3200000    // g1 [NN*C1]; aliased by `stage` during sort (NTOT ints)
#define OFF_ALS1  6400000
#define OFF_ALD1  6800000
#define OFF_HM    7200000    // int H[CH*NCB] = 50176
#define OFF_BASEK 7251000    // int basek[NCB*CH] = 50176
#define OFF_BBASE 7302000    // int bbase[NCB+1]
#define OFF_OFFS  7302400    // int offs[NN+1]
#define OFF_SRC   7352500    // int ssrc[NTOT]
// end = 9,002,500 floats = 36.0 MB (R1 used 37.4 MB successfully)

// ---------------- K1: h1 = x @ W1  (50000x256 @ 256x64) ----------------
__global__ __launch_bounds__(256) void k_gemm1(const float* __restrict__ x,
                                               const float* __restrict__ W1,
                                               float* __restrict__ h1) {
    __shared__ float xs[64][68];
    __shared__ float ws[64][64];
    const int tid = threadIdx.x;
    const int tx = tid & 15, ty = tid >> 4;
    const int r0 = blockIdx.x * 64;
    float acc[4][4] = {};
    for (int k0 = 0; k0 < FIN; k0 += 64) {
        #pragma unroll
        for (int it = 0; it < 4; ++it) {
            int rloc = it * 16 + ty;
            int grow = r0 + rloc;
            float4 v = make_float4(0.f, 0.f, 0.f, 0.f);
            if (grow < NN) v = *(const float4*)(&x[(size_t)grow * FIN + k0 + tx * 4]);
            *(float4*)(&xs[rloc][tx * 4]) = v;
        }
        #pragma unroll
        for (int it = 0; it < 4; ++it) {
            int kk = it * 16 + ty;
            float4 v = *(const float4*)(&W1[(size_t)(k0 + kk) * C1 + tx * 4]);
            *(float4*)(&ws[kk][tx * 4]) = v;
        }
        __syncthreads();
        #pragma unroll 8
        for (int kk = 0; kk < 64; ++kk) {
            float4 wv = *(const float4*)(&ws[kk][tx * 4]);
            #pragma unroll
            for (int m = 0; m < 4; ++m) {
                float xv = xs[m * 16 + ty][kk];
                acc[m][0] += xv * wv.x;
                acc[m][1] += xv * wv.y;
                acc[m][2] += xv * wv.z;
                acc[m][3] += xv * wv.w;
            }
        }
        __syncthreads();
    }
    #pragma unroll
    for (int m = 0; m < 4; ++m) {
        int grow = r0 + m * 16 + ty;
        if (grow < NN) {
            float4 v = make_float4(acc[m][0], acc[m][1], acc[m][2], acc[m][3]);
            *(float4*)(&h1[(size_t)grow * C1 + tx * 4]) = v;
        }
    }
}

// ---------------- K1b: attention logits per (node, head) ----------------
__global__ __launch_bounds__(256) void k_logits1(const float* __restrict__ h1,
                                                 const float* __restrict__ a_src,
                                                 const float* __restrict__ a_dst,
                                                 float* __restrict__ als,
                                                 float* __restrict__ ald) {
    int i = blockIdx.x * 256 + threadIdx.x;   // i = n*8 + head
    if (i >= NN * NH) return;
    int n = i >> 3, hd = i & 7;
    const float4* hp = (const float4*)(&h1[(size_t)n * C1 + hd * NHID]);
    float4 h0 = hp[0], h1v = hp[1];
    const float4* asp = (const float4*)(&a_src[hd * NHID]);
    float4 a0 = asp[0], a1 = asp[1];
    const float4* adp = (const float4*)(&a_dst[hd * NHID]);
    float4 d0 = adp[0], d1 = adp[1];
    float s = h0.x * a0.x + h0.y * a0.y + h0.z * a0.z + h0.w * a0.w
            + h1v.x * a1.x + h1v.y * a1.y + h1v.z * a1.z + h1v.w * a1.w;
    float d = h0.x * d0.x + h0.y * d0.y + h0.z * d0.z + h0.w * d0.w
            + h1v.x * d1.x + h1v.y * d1.y + h1v.z * d1.z + h1v.w * d1.w;
    als[i] = s;
    ald[i] = d;
}

// ======== deterministic 2-pass counting sort (no global atomics) =========

// pass 1a: per-chunk LDS histogram over coarse buckets
__global__ __launch_bounds__(256) void k_rh(const int* __restrict__ ei,
                                            int* __restrict__ H) {
    __shared__ int lh[NCB];
    int k = blockIdx.x;
    for (int i = threadIdx.x; i < NCB; i += 256) lh[i] = 0;
    __syncthreads();
    int e0 = k * EPC, e1 = min(e0 + EPC, NTOT);
    for (int e = e0 + threadIdx.x; e < e1; e += 256) {
        int d = (e < NE) ? ei[NE + e] : (e - NE);
        atomicAdd(&lh[d >> 8], 1);
    }
    __syncthreads();
    for (int i = threadIdx.x; i < NCB; i += 256) H[k * NCB + i] = lh[i];
}

// pass 1b: per-bucket exclusive scan across chunks
__global__ __launch_bounds__(256) void k_rsA(const int* __restrict__ H,
                                             int* __restrict__ basek,
                                             int* __restrict__ btot) {
    __shared__ int sc[CH];
    int b = blockIdx.x, t = threadIdx.x;
    int v = H[t * NCB + b];
    sc[t] = v;
    __syncthreads();
    for (int s = 1; s < CH; s <<= 1) {
        int u = (t >= s) ? sc[t - s] : 0;
        __syncthreads();
        sc[t] += u;
        __syncthreads();
    }
    basek[b * CH + t] = sc[t] - v;
    if (t == CH - 1) btot[b] = sc[t];
}

// pass 1c: exclusive scan of bucket totals (tiny)
__global__ __launch_bounds__(64) void k_rsB(int* __restrict__ btot,
                                            int* __restrict__ bbase,
                                            int* __restrict__ offs) {
    if (threadIdx.x == 0) {
        int run = 0;
        for (int b = 0; b < NCB; ++b) {
            bbase[b] = run;
            run += btot[b];
        }
        bbase[NCB] = run;     // == NTOT
        offs[NN] = NTOT;
    }
}

// pass 1d: scatter packed (src<<8 | dst&255) into bucket-major stage
__global__ __launch_bounds__(256) void k_rscatter(const int* __restrict__ ei,
                                                  const int* __restrict__ basek,
                                                  const int* __restrict__ bbase,
                                                  int* __restrict__ stage) {
    __shared__ int lcur[NCB];
    int k = blockIdx.x;
    for (int i = threadIdx.x; i < NCB; i += 256)
        lcur[i] = bbase[i] + basek[i * CH + k];
    __syncthreads();
    int e0 = k * EPC, e1 = min(e0 + EPC, NTOT);
    for (int e = e0 + threadIdx.x; e < e1; e += 256) {
        int s, d;
        if (e < NE) { s = ei[e]; d = ei[NE + e]; }
        else        { s = e - NE; d = s; }
        int pos = atomicAdd(&lcur[d >> 8], 1);
        stage[pos] = (s << 8) | (d & 255);
    }
}

// pass 2: block per coarse bucket — local hist, scan -> offs, scatter -> ssrc
__global__ __launch_bounds__(256) void k_fsort(const int* __restrict__ stage,
                                               const int* __restrict__ bbase,
                                               int* __restrict__ offs,
                                               int* __restrict__ ssrc) {
    __shared__ int lc[256];
    __shared__ int ls[256];
    __shared__ int lcur[256];
    int b = blockIdx.x, t = threadIdx.x;
    int base = bbase[b];
    int n = bbase[b + 1] - base;
    lc[t] = 0;
    __syncthreads();
    const int* sp = &stage[base];
    for (int i = t; i < n; i += 256) atomicAdd(&lc[sp[i] & 255], 1);
    __syncthreads();
    int v = lc[t];
    ls[t] = v;
    __syncthreads();
    for (int s = 1; s < 256; s <<= 1) {
        int u = (t >= s) ? ls[t - s] : 0;
        __syncthreads();
        ls[t] += u;
        __syncthreads();
    }
    int excl = ls[t] - v;
    int d = b * 256 + t;
    if (d < NN) offs[d] = base + excl;
    lcur[t] = base + excl;
    __syncthreads();
    for (int i = t; i < n; i += 256) {
        int u = sp[i];
        int pos = atomicAdd(&lcur[u & 255], 1);
        ssrc[pos] = u >> 8;
    }
}

// ---------------- K2: layer-1 aggregation, gather side (no atomics) -------
__global__ __launch_bounds__(256) void k_agg1(const int* __restrict__ offs,
                                              const int* __restrict__ src,
                                              const float* __restrict__ h1,
                                              const float* __restrict__ als,
                                              const float* __restrict__ ald,
                                              const float* __restrict__ b1,
                                              float* __restrict__ g1) {
    int d = blockIdx.x * 4 + (threadIdx.x >> 6);
    if (d >= NN) return;
    int c = threadIdx.x & 63;
    int h = c >> 3;
    int beg = offs[d], end = offs[d + 1];
    float aldv = ald[d * NH + h];
    float acc = 0.f, den = 0.f;
    int i = beg;
    for (; i + 1 < end; i += 2) {
        int s0 = src[i], s1 = src[i + 1];
        float l0 = als[s0 * NH + h] + aldv;
        float l1 = als[s1 * NH + h] + aldv;
        l0 = l0 > 0.f ? l0 : 0.2f * l0;
        l1 = l1 > 0.f ? l1 : 0.2f * l1;
        float e0 = __expf(l0), e1 = __expf(l1);
        acc += e0 * h1[(size_t)s0 * C1 + c] + e1 * h1[(size_t)s1 * C1 + c];
        den += e0 + e1;
    }
    if (i < end) {
        int s0 = src[i];
        float l0 = als[s0 * NH + h] + aldv;
        l0 = l0 > 0.f ? l0 : 0.2f * l0;
        float e0 = __expf(l0);
        acc += e0 * h1[(size_t)s0 * C1 + c];
        den += e0;
    }
    float o = acc / den + b1[c];
    g1[(size_t)d * C1 + c] = o > 0.f ? o : (__expf(o) - 1.f);
}

// ---------------- K3: GEMM2 (64->16) + layer-2 logits ----------------
__global__ __launch_bounds__(256) void k_gemm2(const float* __restrict__ g1,
                                               const float* __restrict__ W2,
                                               const float* __restrict__ as2,
                                               const float* __restrict__ ad2,
                                               float* __restrict__ h2,
                                               float* __restrict__ als2,
                                               float* __restrict__ ald2) {
    __shared__ float w2s[C1][NC];
    __shared__ float hact[16][C1 + 4];
    int tid = threadIdx.x;
    for (int i = tid; i < C1 * NC; i += 256) w2s[i >> 4][i & 15] = W2[i];
    int ln = tid >> 4, j = tid & 15;
    int n = blockIdx.x * 16 + ln;
    if (n < NN) {
        float4 v = *(const float4*)(&g1[(size_t)n * C1 + j * 4]);
        *(float4*)(&hact[ln][j * 4]) = v;
    }
    __syncthreads();
    if (n < NN) {
        float sum = 0.f;
        #pragma unroll
        for (int c = 0; c < C1; ++c) sum += hact[ln][c] * w2s[c][j];
        h2[(size_t)n * NC + j] = sum;
        float ps = sum * as2[j], pd = sum * ad2[j];
        #pragma unroll
        for (int w = 1; w < 16; w <<= 1) {
            ps += __shfl_xor(ps, w);
            pd += __shfl_xor(pd, w);
        }
        if (j == 0) { als2[n] = ps; ald2[n] = pd; }
    }
}

// ---------------- K4: layer-2 aggregation + log_softmax ----------------
__global__ __launch_bounds__(256) void k_agg2(const int* __restrict__ offs,
                                              const int* __restrict__ src,
                                              const float* __restrict__ h2,
                                              const float* __restrict__ als2,
                                              const float* __restrict__ ald2,
                                              const float* __restrict__ b2,
                                              float* __restrict__ out) {
    int d = blockIdx.x * 16 + (threadIdx.x >> 4);
    if (d >= NN) return;
    int c = threadIdx.x & 15;
    int beg = offs[d], end = offs[d + 1];
    float aldv = ald2[d];
    float acc = 0.f, den = 0.f;
    int i = beg;
    for (; i + 1 < end; i += 2) {
        int s0 = src[i], s1 = src[i + 1];
        float l0 = als2[s0] + aldv;
        float l1 = als2[s1] + aldv;
        l0 = l0 > 0.f ? l0 : 0.2f * l0;
        l1 = l1 > 0.f ? l1 : 0.2f * l1;
        float e0 = __expf(l0), e1 = __expf(l1);
        acc += e0 * h2[(size_t)s0 * NC + c] + e1 * h2[(size_t)s1 * NC + c];
        den += e0 + e1;
    }
    if (i < end) {
        int s0 = src[i];
        float l0 = als2[s0] + aldv;
        l0 = l0 > 0.f ? l0 : 0.2f * l0;
        float e0 = __expf(l0);
        acc += e0 * h2[(size_t)s0 * NC + c];
        den += e0;
    }
    float o = acc / den + b2[c];
    float m = o;
    #pragma unroll
    for (int w = 1; w < 16; w <<= 1) m = fmaxf(m, __shfl_xor(m, w));
    float ex = __expf(o - m);
    float sm = ex;
    #pragma unroll
    for (int w = 1; w < 16; w <<= 1) sm += __shfl_xor(sm, w);
    out[(size_t)d * NC + c] = o - m - __logf(sm);
}

extern "C" void kernel_launch(void* const* d_in, const int* in_sizes, int n_in,
                              void* d_out, int out_size, void* d_ws, size_t ws_size,
                              hipStream_t stream) {
    const float* x   = (const float*)d_in[0];
    const int*   ei  = (const int*)  d_in[1];
    const float* W1  = (const float*)d_in[2];
    const float* as1 = (const float*)d_in[3];
    const float* ad1 = (const float*)d_in[4];
    const float* b1  = (const float*)d_in[5];
    const float* W2  = (const float*)d_in[6];
    const float* as2 = (const float*)d_in[7];
    const float* ad2 = (const float*)d_in[8];
    const float* b2  = (const float*)d_in[9];
    float* ws  = (float*)d_ws;
    float* out = (float*)d_out;

    float* h1   = ws + OFF_H1;
    float* g1   = ws + OFF_G1;
    float* als1 = ws + OFF_ALS1;
    float* ald1 = ws + OFF_ALD1;
    float* h2   = ws + OFF_H2;
    float* als2 = ws + OFF_ALS2;
    float* ald2 = ws + OFF_ALD2;
    int* H      = (int*)(ws + OFF_HM);
    int* basek  = (int*)(ws + OFF_BASEK);
    int* bbase  = (int*)(ws + OFF_BBASE);
    int* offs   = (int*)(ws + OFF_OFFS);
    int* ssrc   = (int*)(ws + OFF_SRC);
    int* stage  = (int*)(ws + OFF_G1);   // aliases g1 (dead before k_agg1 writes g1)

    k_gemm1   <<<(NN + 63) / 64,        256, 0, stream>>>(x, W1, h1);
    k_logits1 <<<(NN * NH + 255) / 256, 256, 0, stream>>>(h1, as1, ad1, als1, ald1);
    k_rh      <<<CH,                    256, 0, stream>>>(ei, H);
    k_rsA     <<<NCB,                   256, 0, stream>>>(H, basek, bbase + NCB + 2 /*btot scratch*/);
    k_rsB     <<<1,                      64, 0, stream>>>(bbase + NCB + 2, bbase, offs);
    k_rscatter<<<CH,                    256, 0, stream>>>(ei, basek, bbase, stage);
    k_fsort   <<<NCB,                   256, 0, stream>>>(stage, bbase, offs, ssrc);
    k_agg1    <<<(NN + 3) / 4,          256, 0, stream>>>(offs, ssrc, h1, als1, ald1, b1, g1);
    k_gemm2   <<<(NN + 15) / 16,        256, 0, stream>>>(g1, W2, as2, ad2, h2, als2, ald2);
    k_agg2    <<<(NN + 15) / 16,        256, 0, stream>>>(offs, ssrc, h2, als2, ald2, b2, out);
}

// Round 5
// 179.913 us; speedup vs baseline: 3.3836x; 1.2853x over previous
//
#include <hip/hip_runtime.h>
#include <hip/hip_fp16.h>

#define NN   50000
#define FIN  256
#define C1   64        // HEADS*HID
#define NH   8
#define NHID 8
#define NC   16
#define NE   1600000
#define NTOT (NE + NN)

#define CH   256                        // pass-1 chunks
#define EPC  ((NTOT + CH - 1) / CH)     // 6446 edges per chunk
#define NCB  196                        // coarse buckets: dst>>8

// ---- workspace layout (float-indexed), ~36.0 MB total ----
// [0, 1.6M): h1h (fp16, NN*64 halves); after k_agg1 it dies and the region is
//            reused by gemm2: h2 @0 (800K), als2 @800000, ald2 @850000.
#define OFF_H1H   0
#define OFF_H2    0
#define OFF_ALS2  800000
#define OFF_ALD2  850000
#define OFF_G1    3200000    // g1 [NN*C1] f32; aliased by `stage` during sort (NTOT ints)
#define OFF_ALS1  6400000
#define OFF_ALD1  6800000
#define OFF_HM    7200000    // int H[CH*NCB]
#define OFF_BASEK 7251000    // int basek[NCB*CH]
#define OFF_BBASE 7302000    // int bbase[NCB+1] (+btot scratch behind it)
#define OFF_OFFS  7302400    // int offs[NN+1]
#define OFF_SRC   7352500    // int ssrc[NTOT]
// end = 9,002,500 floats = 36.0 MB

// ------- K1: h1 = x @ W1, fused epilogue: fp16 h1 store + attention logits --
__global__ __launch_bounds__(256) void k_gemm1(const float* __restrict__ x,
                                               const float* __restrict__ W1,
                                               const float* __restrict__ as1,
                                               const float* __restrict__ ad1,
                                               __half* __restrict__ h1h,
                                               float* __restrict__ als,
                                               float* __restrict__ ald) {
    __shared__ float xs[64][68];
    __shared__ float ws[64][64];
    const int tid = threadIdx.x;
    const int tx = tid & 15, ty = tid >> 4;
    const int r0 = blockIdx.x * 64;
    float acc[4][4] = {};
    for (int k0 = 0; k0 < FIN; k0 += 64) {
        #pragma unroll
        for (int it = 0; it < 4; ++it) {
            int rloc = it * 16 + ty;
            int grow = r0 + rloc;
            float4 v = make_float4(0.f, 0.f, 0.f, 0.f);
            if (grow < NN) v = *(const float4*)(&x[(size_t)grow * FIN + k0 + tx * 4]);
            *(float4*)(&xs[rloc][tx * 4]) = v;
        }
        #pragma unroll
        for (int it = 0; it < 4; ++it) {
            int kk = it * 16 + ty;
            float4 v = *(const float4*)(&W1[(size_t)(k0 + kk) * C1 + tx * 4]);
            *(float4*)(&ws[kk][tx * 4]) = v;
        }
        __syncthreads();
        #pragma unroll 8
        for (int kk = 0; kk < 64; ++kk) {
            float4 wv = *(const float4*)(&ws[kk][tx * 4]);
            #pragma unroll
            for (int m = 0; m < 4; ++m) {
                float xv = xs[m * 16 + ty][kk];
                acc[m][0] += xv * wv.x;
                acc[m][1] += xv * wv.y;
                acc[m][2] += xv * wv.z;
                acc[m][3] += xv * wv.w;
            }
        }
        __syncthreads();
    }
    // epilogue: channels tx*4..tx*4+3 all belong to head tx>>1
    const float4 asv = *(const float4*)(&as1[tx * 4]);
    const float4 adv = *(const float4*)(&ad1[tx * 4]);
    #pragma unroll
    for (int m = 0; m < 4; ++m) {
        int grow = r0 + m * 16 + ty;
        float ps = acc[m][0] * asv.x + acc[m][1] * asv.y + acc[m][2] * asv.z + acc[m][3] * asv.w;
        float pd = acc[m][0] * adv.x + acc[m][1] * adv.y + acc[m][2] * adv.z + acc[m][3] * adv.w;
        ps += __shfl_xor(ps, 1);
        pd += __shfl_xor(pd, 1);
        if (grow < NN) {
            __half2* hp = (__half2*)(&h1h[(size_t)grow * C1 + tx * 4]);
            hp[0] = __floats2half2_rn(acc[m][0], acc[m][1]);
            hp[1] = __floats2half2_rn(acc[m][2], acc[m][3]);
            if ((tx & 1) == 0) {
                als[grow * NH + (tx >> 1)] = ps;
                ald[grow * NH + (tx >> 1)] = pd;
            }
        }
    }
}

// ======== deterministic 2-pass counting sort (no global atomics) =========
__global__ __launch_bounds__(256) void k_rh(const int* __restrict__ ei,
                                            int* __restrict__ H) {
    __shared__ int lh[NCB];
    int k = blockIdx.x;
    for (int i = threadIdx.x; i < NCB; i += 256) lh[i] = 0;
    __syncthreads();
    int e0 = k * EPC, e1 = min(e0 + EPC, NTOT);
    for (int e = e0 + threadIdx.x; e < e1; e += 256) {
        int d = (e < NE) ? ei[NE + e] : (e - NE);
        atomicAdd(&lh[d >> 8], 1);
    }
    __syncthreads();
    for (int i = threadIdx.x; i < NCB; i += 256) H[k * NCB + i] = lh[i];
}

__global__ __launch_bounds__(256) void k_rsA(const int* __restrict__ H,
                                             int* __restrict__ basek,
                                             int* __restrict__ btot) {
    __shared__ int sc[CH];
    int b = blockIdx.x, t = threadIdx.x;
    int v = H[t * NCB + b];
    sc[t] = v;
    __syncthreads();
    for (int s = 1; s < CH; s <<= 1) {
        int u = (t >= s) ? sc[t - s] : 0;
        __syncthreads();
        sc[t] += u;
        __syncthreads();
    }
    basek[b * CH + t] = sc[t] - v;
    if (t == CH - 1) btot[b] = sc[t];
}

__global__ __launch_bounds__(64) void k_rsB(int* __restrict__ btot,
                                            int* __restrict__ bbase,
                                            int* __restrict__ offs) {
    if (threadIdx.x == 0) {
        int run = 0;
        for (int b = 0; b < NCB; ++b) {
            bbase[b] = run;
            run += btot[b];
        }
        bbase[NCB] = run;
        offs[NN] = NTOT;
    }
}

__global__ __launch_bounds__(256) void k_rscatter(const int* __restrict__ ei,
                                                  const int* __restrict__ basek,
                                                  const int* __restrict__ bbase,
                                                  int* __restrict__ stage) {
    __shared__ int lcur[NCB];
    int k = blockIdx.x;
    for (int i = threadIdx.x; i < NCB; i += 256)
        lcur[i] = bbase[i] + basek[i * CH + k];
    __syncthreads();
    int e0 = k * EPC, e1 = min(e0 + EPC, NTOT);
    for (int e = e0 + threadIdx.x; e < e1; e += 256) {
        int s, d;
        if (e < NE) { s = ei[e]; d = ei[NE + e]; }
        else        { s = e - NE; d = s; }
        int pos = atomicAdd(&lcur[d >> 8], 1);
        stage[pos] = (s << 8) | (d & 255);
    }
}

__global__ __launch_bounds__(256) void k_fsort(const int* __restrict__ stage,
                                               const int* __restrict__ bbase,
                                               int* __restrict__ offs,
                                               int* __restrict__ ssrc) {
    __shared__ int lc[256];
    __shared__ int ls[256];
    __shared__ int lcur[256];
    int b = blockIdx.x, t = threadIdx.x;
    int base = bbase[b];
    int n = bbase[b + 1] - base;
    lc[t] = 0;
    __syncthreads();
    const int* sp = &stage[base];
    for (int i = t; i < n; i += 256) atomicAdd(&lc[sp[i] & 255], 1);
    __syncthreads();
    int v = lc[t];
    ls[t] = v;
    __syncthreads();
    for (int s = 1; s < 256; s <<= 1) {
        int u = (t >= s) ? ls[t - s] : 0;
        __syncthreads();
        ls[t] += u;
        __syncthreads();
    }
    int excl = ls[t] - v;
    int d = b * 256 + t;
    if (d < NN) offs[d] = base + excl;
    lcur[t] = base + excl;
    __syncthreads();
    for (int i = t; i < n; i += 256) {
        int u = sp[i];
        int pos = atomicAdd(&lcur[u & 255], 1);
        ssrc[pos] = u >> 8;
    }
}

// ------- K2: layer-1 aggregation, 8-edge rounds, dedup'd exp, fp16 gather --
// one wave per dst node. lane l: computes weight for (edge l>>3, head l&7);
// accumulates channel c=l (head c>>3).
__global__ __launch_bounds__(256) void k_agg1(const int* __restrict__ offs,
                                              const int* __restrict__ src,
                                              const __half* __restrict__ h1h,
                                              const float* __restrict__ als,
                                              const float* __restrict__ ald,
                                              const float* __restrict__ b1,
                                              float* __restrict__ g1) {
    int d = blockIdx.x * 4 + (threadIdx.x >> 6);
    if (d >= NN) return;
    const int l = threadIdx.x & 63;
    const int c = l;            // accumulation channel
    const int h = c >> 3;       // accumulation head
    const int sub = l >> 3;     // edge slot this lane computes w for
    const int hh = l & 7;       // head this lane computes w for
    int beg = offs[d], end = offs[d + 1];
    float aldv = ald[d * NH + hh];
    float acc = 0.f, den = 0.f;
    for (int r = beg; r < end; r += 8) {
        int e = r + sub;
        bool valid = e < end;
        int s_my = src[valid ? e : (end - 1)];
        float lg = als[s_my * NH + hh] + aldv;
        lg = lg > 0.f ? lg : 0.2f * lg;
        float w = valid ? __expf(lg) : 0.f;
        #pragma unroll
        for (int i = 0; i < 8; ++i) {
            int sv = __builtin_amdgcn_readlane(s_my, i * 8);   // wave-uniform src
            float wv = __shfl(w, i * 8 + h);
            float hv = __half2float(h1h[(size_t)sv * C1 + c]);
            acc += wv * hv;
            den += wv;
        }
    }
    float o = acc / den + b1[c];
    g1[(size_t)d * C1 + c] = o > 0.f ? o : (__expf(o) - 1.f);
}

// ---------------- K3: GEMM2 (64->16) + layer-2 logits ----------------
__global__ __launch_bounds__(256) void k_gemm2(const float* __restrict__ g1,
                                               const float* __restrict__ W2,
                                               const float* __restrict__ as2,
                                               const float* __restrict__ ad2,
                                               float* __restrict__ h2,
                                               float* __restrict__ als2,
                                               float* __restrict__ ald2) {
    __shared__ float w2s[C1][NC];
    __shared__ float hact[16][C1 + 4];
    int tid = threadIdx.x;
    for (int i = tid; i < C1 * NC; i += 256) w2s[i >> 4][i & 15] = W2[i];
    int ln = tid >> 4, j = tid & 15;
    int n = blockIdx.x * 16 + ln;
    if (n < NN) {
        float4 v = *(const float4*)(&g1[(size_t)n * C1 + j * 4]);
        *(float4*)(&hact[ln][j * 4]) = v;
    }
    __syncthreads();
    if (n < NN) {
        float sum = 0.f;
        #pragma unroll
        for (int c = 0; c < C1; ++c) sum += hact[ln][c] * w2s[c][j];
        h2[(size_t)n * NC + j] = sum;
        float ps = sum * as2[j], pd = sum * ad2[j];
        #pragma unroll
        for (int w = 1; w < 16; w <<= 1) {
            ps += __shfl_xor(ps, w);
            pd += __shfl_xor(pd, w);
        }
        if (j == 0) { als2[n] = ps; ald2[n] = pd; }
    }
}

// ---------------- K4: layer-2 aggregation + log_softmax ----------------
__global__ __launch_bounds__(256) void k_agg2(const int* __restrict__ offs,
                                              const int* __restrict__ src,
                                              const float* __restrict__ h2,
                                              const float* __restrict__ als2,
                                              const float* __restrict__ ald2,
                                              const float* __restrict__ b2,
                                              float* __restrict__ out) {
    int d = blockIdx.x * 16 + (threadIdx.x >> 4);
    if (d >= NN) return;
    int c = threadIdx.x & 15;
    int beg = offs[d], end = offs[d + 1];
    float aldv = ald2[d];
    float acc = 0.f, den = 0.f;
    int i = beg;
    for (; i + 1 < end; i += 2) {
        int s0 = src[i], s1 = src[i + 1];
        float l0 = als2[s0] + aldv;
        float l1 = als2[s1] + aldv;
        l0 = l0 > 0.f ? l0 : 0.2f * l0;
        l1 = l1 > 0.f ? l1 : 0.2f * l1;
        float e0 = __expf(l0), e1 = __expf(l1);
        acc += e0 * h2[(size_t)s0 * NC + c] + e1 * h2[(size_t)s1 * NC + c];
        den += e0 + e1;
    }
    if (i < end) {
        int s0 = src[i];
        float l0 = als2[s0] + aldv;
        l0 = l0 > 0.f ? l0 : 0.2f * l0;
        float e0 = __expf(l0);
        acc += e0 * h2[(size_t)s0 * NC + c];
        den += e0;
    }
    float o = acc / den + b2[c];
    float m = o;
    #pragma unroll
    for (int w = 1; w < 16; w <<= 1) m = fmaxf(m, __shfl_xor(m, w));
    float ex = __expf(o - m);
    float sm = ex;
    #pragma unroll
    for (int w = 1; w < 16; w <<= 1) sm += __shfl_xor(sm, w);
    out[(size_t)d * NC + c] = o - m - __logf(sm);
}

extern "C" void kernel_launch(void* const* d_in, const int* in_sizes, int n_in,
                              void* d_out, int out_size, void* d_ws, size_t ws_size,
                              hipStream_t stream) {
    const float* x   = (const float*)d_in[0];
    const int*   ei  = (const int*)  d_in[1];
    const float* W1  = (const float*)d_in[2];
    const float* as1 = (const float*)d_in[3];
    const float* ad1 = (const float*)d_in[4];
    const float* b1  = (const float*)d_in[5];
    const float* W2  = (const float*)d_in[6];
    const float* as2 = (const float*)d_in[7];
    const float* ad2 = (const float*)d_in[8];
    const float* b2  = (const float*)d_in[9];
    float* ws  = (float*)d_ws;
    float* out = (float*)d_out;

    __half* h1h = (__half*)(ws + OFF_H1H);
    float* g1   = ws + OFF_G1;
    float* als1 = ws + OFF_ALS1;
    float* ald1 = ws + OFF_ALD1;
    float* h2   = ws + OFF_H2;
    float* als2 = ws + OFF_ALS2;
    float* ald2 = ws + OFF_ALD2;
    int* H      = (int*)(ws + OFF_HM);
    int* basek  = (int*)(ws + OFF_BASEK);
    int* bbase  = (int*)(ws + OFF_BBASE);
    int* offs   = (int*)(ws + OFF_OFFS);
    int* ssrc   = (int*)(ws + OFF_SRC);
    int* stage  = (int*)(ws + OFF_G1);   // aliases g1 (dead before k_agg1 writes g1)

    k_gemm1   <<<(NN + 63) / 64, 256, 0, stream>>>(x, W1, as1, ad1, h1h, als1, ald1);
    k_rh      <<<CH,             256, 0, stream>>>(ei, H);
    k_rsA     <<<NCB,            256, 0, stream>>>(H, basek, bbase + NCB + 2 /*btot*/);
    k_rsB     <<<1,               64, 0, stream>>>(bbase + NCB + 2, bbase, offs);
    k_rscatter<<<CH,             256, 0, stream>>>(ei, basek, bbase, stage);
    k_fsort   <<<NCB,            256, 0, stream>>>(stage, bbase, offs, ssrc);
    k_agg1    <<<(NN + 3) / 4,   256, 0, stream>>>(offs, ssrc, h1h, als1, ald1, b1, g1);
    k_gemm2   <<<(NN + 15) / 16, 256, 0, stream>>>(g1, W2, as2, ad2, h2, als2, ald2);
    k_agg2    <<<(NN + 15) / 16, 256, 0, stream>>>(offs, ssrc, h2, als2, ald2, b2, out);
}